// Round 4
// baseline (1464.195 us; speedup 1.0000x reference)
//
#include <hip/hip_runtime.h>

#define BB 16
#define SS 1024
#define NPAD 1024      // padded matrix dim: real 1023 + identity pad row/col
#define NBLK 128
#define NSTEP 8        // NPAD / NBLK

typedef __attribute__((ext_vector_type(8))) __bf16 bf16x8;
typedef __attribute__((ext_vector_type(4))) float f32x4;

// ---------- helpers ----------
__device__ __forceinline__ unsigned int enc_f32(float f) {
  unsigned int u = __float_as_uint(f);
  return (u & 0x80000000u) ? ~u : (u | 0x80000000u);
}
__device__ __forceinline__ float dec_key(unsigned int k) {
  unsigned int u = (k & 0x80000000u) ? (k & 0x7fffffffu) : ~k;
  return __uint_as_float(u);
}

// ---------- K0: init max key ----------
__global__ void __launch_bounds__(64) kinit(unsigned long long* mk) { *mk = 0ull; }

// ---------- K1: global max + argmax of scores ----------
__global__ void __launch_bounds__(256) kmax(const float* __restrict__ sc,
                                            unsigned long long* __restrict__ mk) {
  __shared__ unsigned long long red[256];
  const long long n = (long long)BB * SS * SS;
  unsigned long long best = 0ull;
  for (long long i = (long long)blockIdx.x * 256 + threadIdx.x; i < n;
       i += (long long)gridDim.x * 256) {
    unsigned long long k = ((unsigned long long)enc_f32(sc[i]) << 32) | (unsigned int)i;
    if (k > best) best = k;
  }
  red[threadIdx.x] = best;
  __syncthreads();
  for (int s = 128; s > 0; s >>= 1) {
    if ((int)threadIdx.x < s) {
      unsigned long long o = red[threadIdx.x + s];
      if (o > red[threadIdx.x]) red[threadIdx.x] = o;
    }
    __syncthreads();
  }
  if (threadIdx.x == 0) atomicMax(mk, red[0]);
}

// ---------- K2: build padded Laplacian minor M ----------
__global__ void __launch_bounds__(256) kbuild(const float* __restrict__ sc,
                                              float* __restrict__ M,
                                              const unsigned long long* __restrict__ mk) {
  __shared__ float red[256];
  const int r = blockIdx.x;
  const int b = blockIdx.y;
  const int t = threadIdx.x;
  float* Mrow = M + ((size_t)b * NPAD + r) * NPAD;
  if (r == NPAD - 1) {
    for (int c = t; c < NPAD; c += 256) Mrow[c] = (c == NPAD - 1) ? 1.0f : 0.0f;
    return;
  }
  const float m = dec_key((unsigned int)(*mk >> 32));
  const int i = r + 1;
  const float* srow = sc + ((size_t)b * SS + i) * SS;
  float part = 0.f;
  for (int j = t; j < SS; j += 256) part += expf(srow[j] - m);
  red[t] = part;
  __syncthreads();
  for (int s = 128; s > 0; s >>= 1) {
    if (t < s) red[t] += red[t + s];
    __syncthreads();
  }
  const float rs = red[0];
  for (int c = t; c < NPAD; c += 256) {
    float v;
    if (c == NPAD - 1) v = 0.0f;
    else {
      v = -expf(srow[c + 1] - m);
      if (c == r) v += rs;
    }
    Mrow[c] = v;
  }
}

// ---------- fused K3a+K3b: copy column panel to T (128 blocks) + diag inverse (16 blocks) ----------
// Diag inverse = block-GJ at 16x16 granularity: 8 sub-steps; pivot 16x16 inverted by
// wave 0 via __shfl (no barriers), block row/col/trailing updates by all 256 threads.
// 4 barriers per sub-step (32 total) vs 256 for scalar GJ (prev: 79us latency-bound).
__global__ void __launch_bounds__(256) kcopydiag(const float* __restrict__ M,
                                                 float* __restrict__ T,
                                                 float* __restrict__ D, int kb) {
  const int x = blockIdx.x;
  const int t = threadIdx.x;
  if (x < NSTEP * BB) {
    // copy tile (rt, kb) of batch b into T
    const int rt = x >> 4, b = x & 15;
    const float* src = M + ((size_t)b * NPAD + rt * NBLK) * NPAD + kb * NBLK;
    float* dst = T + ((size_t)b * NPAD + rt * NBLK) * NBLK;
    const int c = (t & 31) * 4, r0 = t >> 5;
    for (int r = r0; r < NBLK; r += 8) {
      float4 v = *(const float4*)(src + (size_t)r * NPAD + c);
      *(float4*)(dst + r * NBLK + c) = v;
    }
    return;
  }
  __shared__ float ROWP[8 * 256];  // ROWP[j*256 + row*16 + col] : old pivot block-row
  __shared__ float COLP[8 * 272];  // COLP[i*272 + row*17 + col] : old pivot block-col (+pad)
  __shared__ float NROW[8 * 256];  // new (scaled) pivot block-row
  __shared__ float ELDS[16 * 17];  // inv of 16x16 pivot
  const int b = x - NSTEP * BB;
  const int tx = t & 15, ty = t >> 4;
  const float* src = M + ((size_t)b * NPAD + kb * NBLK) * NPAD + kb * NBLK;
  // r[ii][jj] = element (ty+16*ii, tx+16*jj); sub-block (ii,jj) has one element/thread
  float r[8][8];
#pragma unroll
  for (int ii = 0; ii < 8; ii++)
#pragma unroll
    for (int jj = 0; jj < 8; jj++)
      r[ii][jj] = src[(size_t)(ty + 16 * ii) * NPAD + tx + 16 * jj];

#pragma unroll
  for (int s = 0; s < 8; ++s) {
    // publish old pivot row/col panels
#pragma unroll
    for (int jj = 0; jj < 8; ++jj) ROWP[jj * 256 + ty * 16 + tx] = r[s][jj];
#pragma unroll
    for (int ii = 0; ii < 8; ++ii) COLP[ii * 272 + ty * 17 + tx] = r[ii][s];
    __syncthreads();
    // wave 0: invert 16x16 pivot sub-block in registers with shuffles
    if (t < 64) {
      const int i = t & 15, j4 = t >> 4;
      float e[4];
      float4 ev = *(const float4*)&ROWP[s * 256 + i * 16 + 4 * j4];
      e[0] = ev.x; e[1] = ev.y; e[2] = ev.z; e[3] = ev.w;
#pragma unroll
      for (int k = 0; k < 16; ++k) {
        const float piv = __shfl(e[k & 3], k + 16 * (k >> 2), 64);
        const float pinv = 1.0f / piv;
        float rowv[4];
#pragma unroll
        for (int c = 0; c < 4; ++c) rowv[c] = __shfl(e[c], k + (t & 48), 64);
        const float colv = __shfl(e[k & 3], i + 16 * (k >> 2), 64);
        const float cp = colv * pinv;
        const bool myrow = (i == k);
#pragma unroll
        for (int c = 0; c < 4; ++c) {
          const bool zer = (4 * j4 + c == k);
          if (myrow) {
            e[c] = zer ? pinv : rowv[c] * pinv;
          } else {
            const float old = zer ? 0.0f : e[c];
            e[c] = old - cp * (zer ? 1.0f : rowv[c]);
          }
        }
      }
#pragma unroll
      for (int c = 0; c < 4; ++c) ELDS[i * 17 + 4 * j4 + c] = e[c];
    }
    __syncthreads();
    float Erow[16], Ecol[16];
#pragma unroll
    for (int m = 0; m < 16; ++m) {
      Erow[m] = ELDS[ty * 17 + m];
      Ecol[m] = ELDS[m * 17 + tx];
    }
    // new pivot block-row: S[s][j] = E * Sold[s][j]
#pragma unroll
    for (int jj = 0; jj < 8; ++jj) {
      if (jj == s) continue;
      float acc = 0.f;
#pragma unroll
      for (int m = 0; m < 16; ++m) acc += Erow[m] * ROWP[jj * 256 + m * 16 + tx];
      r[s][jj] = acc;
      NROW[jj * 256 + ty * 16 + tx] = acc;
    }
    r[s][s] = ELDS[ty * 17 + tx];
    // new pivot block-col: S[i][s] = -Sold[i][s] * E
#pragma unroll
    for (int ii = 0; ii < 8; ++ii) {
      if (ii == s) continue;
      float acc = 0.f;
#pragma unroll
      for (int m = 0; m < 16; ++m) acc += COLP[ii * 272 + ty * 17 + m] * Ecol[m];
      r[ii][s] = -acc;
    }
    __syncthreads();
    // trailing: S[i][j] -= Sold[i][s] * Snew[s][j]
#pragma unroll
    for (int ii = 0; ii < 8; ++ii) {
      if (ii == s) continue;
      float cv[16];
#pragma unroll
      for (int m = 0; m < 16; ++m) cv[m] = COLP[ii * 272 + ty * 17 + m];
#pragma unroll
      for (int jj = 0; jj < 8; ++jj) {
        if (jj == s) continue;
        float acc = r[ii][jj];
#pragma unroll
        for (int m = 0; m < 16; ++m) acc -= cv[m] * NROW[jj * 256 + m * 16 + tx];
        r[ii][jj] = acc;
      }
    }
    __syncthreads();
  }
  float* dst = D + (size_t)b * NBLK * NBLK;
#pragma unroll
  for (int ii = 0; ii < 8; ii++)
#pragma unroll
    for (int jj = 0; jj < 8; jj++)
      dst[(size_t)(ty + 16 * ii) * NBLK + tx + 16 * jj] = r[ii][jj];
}

// ---------- 128x128x128 GEMM core via split-bf16 MFMA: C = beta*C + alpha*A*B ----------
__device__ __forceinline__ void gemm128(const float* __restrict__ A, int lda,
                                        const float* __restrict__ B, int ldb,
                                        float* __restrict__ C, int ldc,
                                        float alpha, float beta) {
  __shared__ __bf16 Ah[4096], Al[4096], Bh[4096], Bl[4096];
  const int t = threadIdx.x;
  const int l = t & 63, w = t >> 6;
  const int ic = t & 127, kh = t >> 7;
  const int rbase = (w & 1) * 4, cbase = (w >> 1) * 4;

  f32x4 acc[4][4];
#pragma unroll
  for (int i = 0; i < 4; i++)
#pragma unroll
    for (int j = 0; j < 4; j++) acc[i][j] = (f32x4){0.f, 0.f, 0.f, 0.f};

  for (int k0 = 0; k0 < NBLK; k0 += 32) {
    {
      const float* ap = A + (size_t)ic * lda + k0 + kh * 16;
      float f[16];
      *(float4*)(f + 0)  = *(const float4*)(ap + 0);
      *(float4*)(f + 4)  = *(const float4*)(ap + 4);
      *(float4*)(f + 8)  = *(const float4*)(ap + 8);
      *(float4*)(f + 12) = *(const float4*)(ap + 12);
      const int base = ((ic >> 4) * 4 + kh * 2) * 16 + (ic & 15);
#pragma unroll
      for (int g = 0; g < 2; ++g) {
        bf16x8 hv, lv;
#pragma unroll
        for (int j = 0; j < 8; ++j) {
          float x = f[g * 8 + j];
          __bf16 h = (__bf16)x;
          hv[j] = h;
          lv[j] = (__bf16)(x - (float)h);
        }
        *(bf16x8*)&Ah[(size_t)(base + g * 16) * 8] = hv;
        *(bf16x8*)&Al[(size_t)(base + g * 16) * 8] = lv;
      }
    }
    {
      const float* bp = B + (size_t)(k0 + kh * 16) * ldb + ic;
      float f[16];
#pragma unroll
      for (int kk = 0; kk < 16; ++kk) f[kk] = bp[(size_t)kk * ldb];
      const int base = ((ic >> 4) * 4 + kh * 2) * 16 + (ic & 15);
#pragma unroll
      for (int g = 0; g < 2; ++g) {
        bf16x8 hv, lv;
#pragma unroll
        for (int j = 0; j < 8; ++j) {
          float x = f[g * 8 + j];
          __bf16 h = (__bf16)x;
          hv[j] = h;
          lv[j] = (__bf16)(x - (float)h);
        }
        *(bf16x8*)&Bh[(size_t)(base + g * 16) * 8] = hv;
        *(bf16x8*)&Bl[(size_t)(base + g * 16) * 8] = lv;
      }
    }
    __syncthreads();
    bf16x8 a_h[4], a_l[4];
#pragma unroll
    for (int rt = 0; rt < 4; ++rt) {
      a_h[rt] = *(const bf16x8*)&Ah[(size_t)((rbase + rt) * 64 + l) * 8];
      a_l[rt] = *(const bf16x8*)&Al[(size_t)((rbase + rt) * 64 + l) * 8];
    }
#pragma unroll
    for (int ct = 0; ct < 4; ++ct) {
      bf16x8 b_h = *(const bf16x8*)&Bh[(size_t)((cbase + ct) * 64 + l) * 8];
      bf16x8 b_l = *(const bf16x8*)&Bl[(size_t)((cbase + ct) * 64 + l) * 8];
#pragma unroll
      for (int rt = 0; rt < 4; ++rt) {
        acc[rt][ct] = __builtin_amdgcn_mfma_f32_16x16x32_bf16(a_h[rt], b_h, acc[rt][ct], 0, 0, 0);
        acc[rt][ct] = __builtin_amdgcn_mfma_f32_16x16x32_bf16(a_h[rt], b_l, acc[rt][ct], 0, 0, 0);
        acc[rt][ct] = __builtin_amdgcn_mfma_f32_16x16x32_bf16(a_l[rt], b_h, acc[rt][ct], 0, 0, 0);
      }
    }
    __syncthreads();
  }
  const int row0 = (w & 1) * 64 + ((l >> 4) << 2);
  const int col0 = (w >> 1) * 64 + (l & 15);
  if (beta == 0.0f) {
#pragma unroll
    for (int rt = 0; rt < 4; ++rt)
#pragma unroll
      for (int ct = 0; ct < 4; ++ct)
#pragma unroll
        for (int r = 0; r < 4; ++r)
          C[(size_t)(row0 + rt * 16 + r) * ldc + col0 + ct * 16] = alpha * acc[rt][ct][r];
  } else {
#pragma unroll
    for (int rt = 0; rt < 4; ++rt)
#pragma unroll
      for (int ct = 0; ct < 4; ++ct)
#pragma unroll
        for (int r = 0; r < 4; ++r) {
          float* cp = C + (size_t)(row0 + rt * 16 + r) * ldc + col0 + ct * 16;
          *cp = beta * (*cp) + alpha * acc[rt][ct][r];
        }
  }
}

// ---------- K3c: pivot block-row scale ----------
__global__ void __launch_bounds__(256) kscale(float* __restrict__ M,
                                              const float* __restrict__ D, int kb) {
  const int jt = blockIdx.x, b = blockIdx.y;
  const float* Dinv = D + (size_t)b * NBLK * NBLK;
  float* Mb = M + (size_t)b * NPAD * NPAD;
  if (jt == kb) {
    const int t = threadIdx.x;
    const int c = (t & 31) * 4, r0 = t >> 5;
    float* dst = Mb + (size_t)(kb * NBLK) * NPAD + kb * NBLK;
    for (int r = r0; r < NBLK; r += 8)
      *(float4*)(dst + (size_t)r * NPAD + c) = *(const float4*)(Dinv + r * NBLK + c);
    return;
  }
  float* Btile = Mb + (size_t)(kb * NBLK) * NPAD + jt * NBLK;
  gemm128(Dinv, NBLK, Btile, NPAD, Btile, NPAD, 1.0f, 0.0f);
}

// ---------- K3d: trailing update (and pivot-column): rows it != kb ----------
__global__ void __launch_bounds__(256) kupdate(float* __restrict__ M,
                                               const float* __restrict__ T,
                                               const float* __restrict__ D, int kb) {
  const int jt = blockIdx.x;
  int it = blockIdx.y; it = (it >= kb) ? it + 1 : it;
  const int b = blockIdx.z;
  float* Mb = M + (size_t)b * NPAD * NPAD;
  const float* Atile = T + ((size_t)b * NPAD + it * NBLK) * NBLK;
  float* Ctile = Mb + (size_t)(it * NBLK) * NPAD + jt * NBLK;
  if (jt == kb) {
    gemm128(Atile, NBLK, D + (size_t)b * NBLK * NBLK, NBLK, Ctile, NPAD, -1.0f, 0.0f);
  } else {
    const float* Btile = Mb + (size_t)(kb * NBLK) * NPAD + jt * NBLK;
    gemm128(Atile, NBLK, Btile, NPAD, Ctile, NPAD, -1.0f, 1.0f);
  }
}

// ---------- K4: epilogue: probs = A .* (Binv[p,p] - Binv[q,p]) + spike ----------
__global__ void __launch_bounds__(256) kfinal(const float* __restrict__ sc,
                                              const float* __restrict__ Minv,
                                              float* __restrict__ out,
                                              const unsigned long long* __restrict__ mk) {
  __shared__ float Ls[64][65];
  __shared__ float Ds[64];
  const int qt = blockIdx.x, pt = blockIdx.y, b = blockIdx.z;
  const int t = threadIdx.x;
  const unsigned long long key = *mk;
  const float m = dec_key((unsigned int)(key >> 32));
  const unsigned int amax = (unsigned int)key;
  const float* Mb = Minv + (size_t)b * NPAD * NPAD;
  const int q0 = qt * 64, p0 = pt * 64;
  {
    const int pp = t & 63, qq0 = t >> 6;
#pragma unroll
    for (int rp = 0; rp < 16; ++rp) {
      const int qq = qq0 + 4 * rp;
      int rrow = q0 + qq - 1; if (rrow < 0) rrow = 0;
      int ccol = p0 + pp - 1; if (ccol < 0) ccol = 0;
      Ls[qq][pp] = Mb[(size_t)rrow * NPAD + ccol];
    }
    if (t < 64) {
      int cc = p0 + t - 1; if (cc < 0) cc = 0;
      Ds[t] = Mb[(size_t)cc * NPAD + cc];
    }
  }
  __syncthreads();
  const int qq = t & 63, pp0 = t >> 6;
#pragma unroll
  for (int rp = 0; rp < 16; ++rp) {
    const int pp = pp0 + 4 * rp;
    const int p = p0 + pp, q = q0 + qq;
    const size_t off = ((size_t)b * SS + p) * SS + q;
    float val = 0.f;
    if (p >= 1) {
      const float a = expf(sc[off] - m);
      const float g = Ds[pp] - ((q >= 1) ? Ls[qq][pp] : 0.f);
      val = a * g;
    }
    if ((unsigned int)off == amax) val += 16.0f;  // d logZ / d m
    out[off] = val;
  }
}

extern "C" void kernel_launch(void* const* d_in, const int* in_sizes, int n_in,
                              void* d_out, int out_size, void* d_ws, size_t ws_size,
                              hipStream_t stream) {
  const float* sc = (const float*)d_in[0];
  float* out = (float*)d_out;
  char* ws = (char*)d_ws;
  unsigned long long* mk = (unsigned long long*)ws;
  float* M = (float*)(ws + 256);
  float* T = M + (size_t)BB * NPAD * NPAD;
  float* D = T + (size_t)BB * NPAD * NBLK;

  hipLaunchKernelGGL(kinit, dim3(1), dim3(64), 0, stream, mk);
  hipLaunchKernelGGL(kmax, dim3(1024), dim3(256), 0, stream, sc, mk);
  hipLaunchKernelGGL(kbuild, dim3(NPAD, BB), dim3(256), 0, stream, sc, M, mk);
  for (int kb = 0; kb < NSTEP; ++kb) {
    hipLaunchKernelGGL(kcopydiag, dim3(NSTEP * BB + BB), dim3(256), 0, stream, M, T, D, kb);
    hipLaunchKernelGGL(kscale, dim3(NSTEP, BB), dim3(256), 0, stream, M, D, kb);
    hipLaunchKernelGGL(kupdate, dim3(NSTEP, NSTEP - 1, BB), dim3(256), 0, stream, M, T, D, kb);
  }
  hipLaunchKernelGGL(kfinal, dim3(16, 16, BB), dim3(256), 0, stream, sc, M, out, mk);
}

// Round 5
// 1461.726 us; speedup vs baseline: 1.0017x; 1.0017x over previous
//
#include <hip/hip_runtime.h>

#define BB 16
#define SS 1024
#define NPAD 1024      // padded matrix dim: real 1023 + identity pad row/col
#define NBLK 128
#define NSTEP 8        // NPAD / NBLK

typedef __attribute__((ext_vector_type(8))) __bf16 bf16x8;
typedef __attribute__((ext_vector_type(4))) float f32x4;

// ---------- helpers ----------
__device__ __forceinline__ unsigned int enc_f32(float f) {
  unsigned int u = __float_as_uint(f);
  return (u & 0x80000000u) ? ~u : (u | 0x80000000u);
}
__device__ __forceinline__ float dec_key(unsigned int k) {
  unsigned int u = (k & 0x80000000u) ? (k & 0x7fffffffu) : ~k;
  return __uint_as_float(u);
}

// ---------- K0: init max key ----------
__global__ void __launch_bounds__(64) kinit(unsigned long long* mk) { *mk = 0ull; }

// ---------- K1: global max + argmax of scores ----------
__global__ void __launch_bounds__(256) kmax(const float* __restrict__ sc,
                                            unsigned long long* __restrict__ mk) {
  __shared__ unsigned long long red[256];
  const long long n = (long long)BB * SS * SS;
  unsigned long long best = 0ull;
  for (long long i = (long long)blockIdx.x * 256 + threadIdx.x; i < n;
       i += (long long)gridDim.x * 256) {
    unsigned long long k = ((unsigned long long)enc_f32(sc[i]) << 32) | (unsigned int)i;
    if (k > best) best = k;
  }
  red[threadIdx.x] = best;
  __syncthreads();
  for (int s = 128; s > 0; s >>= 1) {
    if ((int)threadIdx.x < s) {
      unsigned long long o = red[threadIdx.x + s];
      if (o > red[threadIdx.x]) red[threadIdx.x] = o;
    }
    __syncthreads();
  }
  if (threadIdx.x == 0) atomicMax(mk, red[0]);
}

// ---------- K2: build padded Laplacian minor M ----------
__global__ void __launch_bounds__(256) kbuild(const float* __restrict__ sc,
                                              float* __restrict__ M,
                                              const unsigned long long* __restrict__ mk) {
  __shared__ float red[256];
  const int r = blockIdx.x;
  const int b = blockIdx.y;
  const int t = threadIdx.x;
  float* Mrow = M + ((size_t)b * NPAD + r) * NPAD;
  if (r == NPAD - 1) {
    for (int c = t; c < NPAD; c += 256) Mrow[c] = (c == NPAD - 1) ? 1.0f : 0.0f;
    return;
  }
  const float m = dec_key((unsigned int)(*mk >> 32));
  const int i = r + 1;
  const float* srow = sc + ((size_t)b * SS + i) * SS;
  float part = 0.f;
  for (int j = t; j < SS; j += 256) part += expf(srow[j] - m);
  red[t] = part;
  __syncthreads();
  for (int s = 128; s > 0; s >>= 1) {
    if (t < s) red[t] += red[t + s];
    __syncthreads();
  }
  const float rs = red[0];
  for (int c = t; c < NPAD; c += 256) {
    float v;
    if (c == NPAD - 1) v = 0.0f;
    else {
      v = -expf(srow[c + 1] - m);
      if (c == r) v += rs;
    }
    Mrow[c] = v;
  }
}

// ---------- fused K3a+K3b: copy column panel to T (128 blocks) + diag inverse (16 blocks) ----------
// Diag inverse = block-GJ at 16x16 granularity, 8 sub-steps, 2 barriers each.
// All operands register-resident: cv[7][16] column panel in VGPRs (occupancy is
// irrelevant: 16 blocks on 256 CUs -> launch_bounds(256,1), spend registers).
// Pivot 16x16 inverted redundantly per-wave via dual shuffle-GJ on P and P^T so both
// Erow (E[ty][*]) and Ecol (E[*][tx]) come from compile-time-component shuffles.
__global__ void __launch_bounds__(256, 1) kcopydiag(const float* __restrict__ M,
                                                    float* __restrict__ T,
                                                    float* __restrict__ D, int kb) {
  const int x = blockIdx.x;
  const int t = threadIdx.x;
  if (x < NSTEP * BB) {
    const int rt = x >> 4, b = x & 15;
    const float* src = M + ((size_t)b * NPAD + rt * NBLK) * NPAD + kb * NBLK;
    float* dst = T + ((size_t)b * NPAD + rt * NBLK) * NBLK;
    const int c = (t & 31) * 4, r0 = t >> 5;
    for (int r = r0; r < NBLK; r += 8) {
      float4 v = *(const float4*)(src + (size_t)r * NPAD + c);
      *(float4*)(dst + r * NBLK + c) = v;
    }
    return;
  }
  __shared__ float ROWP[8 * 256];  // ROWP[jj*256 + row*16 + col]: old pivot block-row
  __shared__ float COLP[8 * 256];  // COLP[ii*256 + row*16 + col]: old pivot block-col
  __shared__ float NROW[8 * 256];  // new (scaled) pivot block-row
  __shared__ float ELDS[256];      // inv of 16x16 pivot
  const int b = x - NSTEP * BB;
  const int tx = t & 15, ty = t >> 4;
  const int l = t & 63, li = l & 15, j4 = l >> 4;
  const float* src = M + ((size_t)b * NPAD + kb * NBLK) * NPAD + kb * NBLK;
  float r[8][8];
#pragma unroll
  for (int ii = 0; ii < 8; ii++)
#pragma unroll
    for (int jj = 0; jj < 8; jj++)
      r[ii][jj] = src[(size_t)(ty + 16 * ii) * NPAD + tx + 16 * jj];

#pragma unroll
  for (int s = 0; s < 8; ++s) {
    // 1. publish old pivot block-row / block-col (conflict-free: addrs 0..63/wave)
#pragma unroll
    for (int jj = 0; jj < 8; ++jj) ROWP[jj * 256 + ty * 16 + tx] = r[s][jj];
#pragma unroll
    for (int ii = 0; ii < 8; ++ii) COLP[ii * 256 + ty * 16 + tx] = r[ii][s];
    __syncthreads();  // barrier A
    // 2. dual shuffle-GJ on P and P^T (redundant in every wave)
    float e[4], et[4];
    {
      float4 ev = *(const float4*)&ROWP[s * 256 + li * 16 + 4 * j4];
      e[0] = ev.x; e[1] = ev.y; e[2] = ev.z; e[3] = ev.w;
      et[0] = ROWP[s * 256 + (4 * j4 + 0) * 16 + li];
      et[1] = ROWP[s * 256 + (4 * j4 + 1) * 16 + li];
      et[2] = ROWP[s * 256 + (4 * j4 + 2) * 16 + li];
      et[3] = ROWP[s * 256 + (4 * j4 + 3) * 16 + li];
    }
#pragma unroll
    for (int k = 0; k < 16; ++k) {
      const float piv = __shfl(e[k & 3], k + 16 * (k >> 2), 64);
      const float pinv = 1.0f / piv;   // P^T shares the same pivot sequence
      float rowv[4], rowvt[4];
#pragma unroll
      for (int c = 0; c < 4; ++c) {
        rowv[c] = __shfl(e[c], k + 16 * j4, 64);
        rowvt[c] = __shfl(et[c], k + 16 * j4, 64);
      }
      const float colv = __shfl(e[k & 3], li + 16 * (k >> 2), 64);
      const float colvt = __shfl(et[k & 3], li + 16 * (k >> 2), 64);
      const bool myrow = (li == k);
      const float cp = colv * pinv, cpt = colvt * pinv;
#pragma unroll
      for (int c = 0; c < 4; ++c) {
        const bool zer = (4 * j4 + c == k);
        if (myrow) {
          e[c] = zer ? pinv : rowv[c] * pinv;
          et[c] = zer ? pinv : rowvt[c] * pinv;
        } else {
          e[c] = (zer ? 0.0f : e[c]) - cp * (zer ? 1.0f : rowv[c]);
          et[c] = (zer ? 0.0f : et[c]) - cpt * (zer ? 1.0f : rowvt[c]);
        }
      }
    }
    if (t < 64) {
      float4 ev; ev.x = e[0]; ev.y = e[1]; ev.z = e[2]; ev.w = e[3];
      *(float4*)&ELDS[li * 16 + 4 * j4] = ev;
    }
    // extract Erow[m]=E[ty][m], Ecol[m]=E[m][tx] (compile-time components)
    float Erow[16], Ecol[16];
#pragma unroll
    for (int m = 0; m < 16; ++m) {
      Erow[m] = __shfl(e[m & 3], ty + 16 * (m >> 2), 64);
      Ecol[m] = __shfl(et[m & 3], tx + 16 * (m >> 2), 64);
    }
    // 3. hoist column panel into registers (b128 reads, m-contiguous)
    float cv[8][16];
#pragma unroll
    for (int ii = 0; ii < 8; ++ii) {
      if (ii == s) continue;
#pragma unroll
      for (int mq = 0; mq < 4; ++mq)
        *(float4*)&cv[ii][4 * mq] = *(const float4*)&COLP[ii * 256 + ty * 16 + 4 * mq];
    }
    // 4. new pivot row: r[s][jj] = E * old_row  (ROWP reads broadcast across ty)
#pragma unroll
    for (int jj = 0; jj < 8; ++jj) {
      if (jj == s) continue;
      float acc = 0.f;
#pragma unroll
      for (int m = 0; m < 16; ++m) acc += Erow[m] * ROWP[jj * 256 + m * 16 + tx];
      r[s][jj] = acc;
      NROW[jj * 256 + ty * 16 + tx] = acc;
    }
    // 5. new pivot col: r[ii][s] = -old_col * E (pure register FMA)
#pragma unroll
    for (int ii = 0; ii < 8; ++ii) {
      if (ii == s) continue;
      float acc = 0.f;
#pragma unroll
      for (int m = 0; m < 16; ++m) acc += cv[ii][m] * Ecol[m];
      r[ii][s] = -acc;
    }
    __syncthreads();  // barrier B
    r[s][s] = ELDS[ty * 16 + tx];
    // 6. trailing: r[ii][jj] -= cv[ii] . nr  (nr loaded once per jj)
#pragma unroll
    for (int jj = 0; jj < 8; ++jj) {
      if (jj == s) continue;
      float nr[16];
#pragma unroll
      for (int m = 0; m < 16; ++m) nr[m] = NROW[jj * 256 + m * 16 + tx];
#pragma unroll
      for (int ii = 0; ii < 8; ++ii) {
        if (ii == s) continue;
        float acc = r[ii][jj];
#pragma unroll
        for (int m = 0; m < 16; ++m) acc -= cv[ii][m] * nr[m];
        r[ii][jj] = acc;
      }
    }
  }
  float* dst = D + (size_t)b * NBLK * NBLK;
#pragma unroll
  for (int ii = 0; ii < 8; ii++)
#pragma unroll
    for (int jj = 0; jj < 8; jj++)
      dst[(size_t)(ty + 16 * ii) * NBLK + tx + 16 * jj] = r[ii][jj];
}

// ---------- 128x128x128 GEMM core via split-bf16 MFMA: C = beta*C + alpha*A*B ----------
__device__ __forceinline__ void gemm128(const float* __restrict__ A, int lda,
                                        const float* __restrict__ B, int ldb,
                                        float* __restrict__ C, int ldc,
                                        float alpha, float beta) {
  __shared__ __bf16 Ah[4096], Al[4096], Bh[4096], Bl[4096];
  const int t = threadIdx.x;
  const int l = t & 63, w = t >> 6;
  const int ic = t & 127, kh = t >> 7;
  const int rbase = (w & 1) * 4, cbase = (w >> 1) * 4;

  f32x4 acc[4][4];
#pragma unroll
  for (int i = 0; i < 4; i++)
#pragma unroll
    for (int j = 0; j < 4; j++) acc[i][j] = (f32x4){0.f, 0.f, 0.f, 0.f};

  for (int k0 = 0; k0 < NBLK; k0 += 32) {
    {
      const float* ap = A + (size_t)ic * lda + k0 + kh * 16;
      float f[16];
      *(float4*)(f + 0)  = *(const float4*)(ap + 0);
      *(float4*)(f + 4)  = *(const float4*)(ap + 4);
      *(float4*)(f + 8)  = *(const float4*)(ap + 8);
      *(float4*)(f + 12) = *(const float4*)(ap + 12);
      const int base = ((ic >> 4) * 4 + kh * 2) * 16 + (ic & 15);
#pragma unroll
      for (int g = 0; g < 2; ++g) {
        bf16x8 hv, lv;
#pragma unroll
        for (int j = 0; j < 8; ++j) {
          float x = f[g * 8 + j];
          __bf16 h = (__bf16)x;
          hv[j] = h;
          lv[j] = (__bf16)(x - (float)h);
        }
        *(bf16x8*)&Ah[(size_t)(base + g * 16) * 8] = hv;
        *(bf16x8*)&Al[(size_t)(base + g * 16) * 8] = lv;
      }
    }
    {
      const float* bp = B + (size_t)(k0 + kh * 16) * ldb + ic;
      float f[16];
#pragma unroll
      for (int kk = 0; kk < 16; ++kk) f[kk] = bp[(size_t)kk * ldb];
      const int base = ((ic >> 4) * 4 + kh * 2) * 16 + (ic & 15);
#pragma unroll
      for (int g = 0; g < 2; ++g) {
        bf16x8 hv, lv;
#pragma unroll
        for (int j = 0; j < 8; ++j) {
          float x = f[g * 8 + j];
          __bf16 h = (__bf16)x;
          hv[j] = h;
          lv[j] = (__bf16)(x - (float)h);
        }
        *(bf16x8*)&Bh[(size_t)(base + g * 16) * 8] = hv;
        *(bf16x8*)&Bl[(size_t)(base + g * 16) * 8] = lv;
      }
    }
    __syncthreads();
    bf16x8 a_h[4], a_l[4];
#pragma unroll
    for (int rt = 0; rt < 4; ++rt) {
      a_h[rt] = *(const bf16x8*)&Ah[(size_t)((rbase + rt) * 64 + l) * 8];
      a_l[rt] = *(const bf16x8*)&Al[(size_t)((rbase + rt) * 64 + l) * 8];
    }
#pragma unroll
    for (int ct = 0; ct < 4; ++ct) {
      bf16x8 b_h = *(const bf16x8*)&Bh[(size_t)((cbase + ct) * 64 + l) * 8];
      bf16x8 b_l = *(const bf16x8*)&Bl[(size_t)((cbase + ct) * 64 + l) * 8];
#pragma unroll
      for (int rt = 0; rt < 4; ++rt) {
        acc[rt][ct] = __builtin_amdgcn_mfma_f32_16x16x32_bf16(a_h[rt], b_h, acc[rt][ct], 0, 0, 0);
        acc[rt][ct] = __builtin_amdgcn_mfma_f32_16x16x32_bf16(a_h[rt], b_l, acc[rt][ct], 0, 0, 0);
        acc[rt][ct] = __builtin_amdgcn_mfma_f32_16x16x32_bf16(a_l[rt], b_h, acc[rt][ct], 0, 0, 0);
      }
    }
    __syncthreads();
  }
  const int row0 = (w & 1) * 64 + ((l >> 4) << 2);
  const int col0 = (w >> 1) * 64 + (l & 15);
  if (beta == 0.0f) {
#pragma unroll
    for (int rt = 0; rt < 4; ++rt)
#pragma unroll
      for (int ct = 0; ct < 4; ++ct)
#pragma unroll
        for (int r = 0; r < 4; ++r)
          C[(size_t)(row0 + rt * 16 + r) * ldc + col0 + ct * 16] = alpha * acc[rt][ct][r];
  } else {
#pragma unroll
    for (int rt = 0; rt < 4; ++rt)
#pragma unroll
      for (int ct = 0; ct < 4; ++ct)
#pragma unroll
        for (int r = 0; r < 4; ++r) {
          float* cp = C + (size_t)(row0 + rt * 16 + r) * ldc + col0 + ct * 16;
          *cp = beta * (*cp) + alpha * acc[rt][ct][r];
        }
  }
}

// ---------- K3c: pivot block-row scale ----------
__global__ void __launch_bounds__(256) kscale(float* __restrict__ M,
                                              const float* __restrict__ D, int kb) {
  const int jt = blockIdx.x, b = blockIdx.y;
  const float* Dinv = D + (size_t)b * NBLK * NBLK;
  float* Mb = M + (size_t)b * NPAD * NPAD;
  if (jt == kb) {
    const int t = threadIdx.x;
    const int c = (t & 31) * 4, r0 = t >> 5;
    float* dst = Mb + (size_t)(kb * NBLK) * NPAD + kb * NBLK;
    for (int r = r0; r < NBLK; r += 8)
      *(float4*)(dst + (size_t)r * NPAD + c) = *(const float4*)(Dinv + r * NBLK + c);
    return;
  }
  float* Btile = Mb + (size_t)(kb * NBLK) * NPAD + jt * NBLK;
  gemm128(Dinv, NBLK, Btile, NPAD, Btile, NPAD, 1.0f, 0.0f);
}

// ---------- K3d: trailing update (and pivot-column): rows it != kb ----------
__global__ void __launch_bounds__(256) kupdate(float* __restrict__ M,
                                               const float* __restrict__ T,
                                               const float* __restrict__ D, int kb) {
  const int jt = blockIdx.x;
  int it = blockIdx.y; it = (it >= kb) ? it + 1 : it;
  const int b = blockIdx.z;
  float* Mb = M + (size_t)b * NPAD * NPAD;
  const float* Atile = T + ((size_t)b * NPAD + it * NBLK) * NBLK;
  float* Ctile = Mb + (size_t)(it * NBLK) * NPAD + jt * NBLK;
  if (jt == kb) {
    gemm128(Atile, NBLK, D + (size_t)b * NBLK * NBLK, NBLK, Ctile, NPAD, -1.0f, 0.0f);
  } else {
    const float* Btile = Mb + (size_t)(kb * NBLK) * NPAD + jt * NBLK;
    gemm128(Atile, NBLK, Btile, NPAD, Ctile, NPAD, -1.0f, 1.0f);
  }
}

// ---------- K4: epilogue: probs = A .* (Binv[p,p] - Binv[q,p]) + spike ----------
__global__ void __launch_bounds__(256) kfinal(const float* __restrict__ sc,
                                              const float* __restrict__ Minv,
                                              float* __restrict__ out,
                                              const unsigned long long* __restrict__ mk) {
  __shared__ float Ls[64][65];
  __shared__ float Ds[64];
  const int qt = blockIdx.x, pt = blockIdx.y, b = blockIdx.z;
  const int t = threadIdx.x;
  const unsigned long long key = *mk;
  const float m = dec_key((unsigned int)(key >> 32));
  const unsigned int amax = (unsigned int)key;
  const float* Mb = Minv + (size_t)b * NPAD * NPAD;
  const int q0 = qt * 64, p0 = pt * 64;
  {
    const int pp = t & 63, qq0 = t >> 6;
#pragma unroll
    for (int rp = 0; rp < 16; ++rp) {
      const int qq = qq0 + 4 * rp;
      int rrow = q0 + qq - 1; if (rrow < 0) rrow = 0;
      int ccol = p0 + pp - 1; if (ccol < 0) ccol = 0;
      Ls[qq][pp] = Mb[(size_t)rrow * NPAD + ccol];
    }
    if (t < 64) {
      int cc = p0 + t - 1; if (cc < 0) cc = 0;
      Ds[t] = Mb[(size_t)cc * NPAD + cc];
    }
  }
  __syncthreads();
  const int qq = t & 63, pp0 = t >> 6;
#pragma unroll
  for (int rp = 0; rp < 16; ++rp) {
    const int pp = pp0 + 4 * rp;
    const int p = p0 + pp, q = q0 + qq;
    const size_t off = ((size_t)b * SS + p) * SS + q;
    float val = 0.f;
    if (p >= 1) {
      const float a = expf(sc[off] - m);
      const float g = Ds[pp] - ((q >= 1) ? Ls[qq][pp] : 0.f);
      val = a * g;
    }
    if ((unsigned int)off == amax) val += 16.0f;  // d logZ / d m
    out[off] = val;
  }
}

extern "C" void kernel_launch(void* const* d_in, const int* in_sizes, int n_in,
                              void* d_out, int out_size, void* d_ws, size_t ws_size,
                              hipStream_t stream) {
  const float* sc = (const float*)d_in[0];
  float* out = (float*)d_out;
  char* ws = (char*)d_ws;
  unsigned long long* mk = (unsigned long long*)ws;
  float* M = (float*)(ws + 256);
  float* T = M + (size_t)BB * NPAD * NPAD;
  float* D = T + (size_t)BB * NPAD * NBLK;

  hipLaunchKernelGGL(kinit, dim3(1), dim3(64), 0, stream, mk);
  hipLaunchKernelGGL(kmax, dim3(1024), dim3(256), 0, stream, sc, mk);
  hipLaunchKernelGGL(kbuild, dim3(NPAD, BB), dim3(256), 0, stream, sc, M, mk);
  for (int kb = 0; kb < NSTEP; ++kb) {
    hipLaunchKernelGGL(kcopydiag, dim3(NSTEP * BB + BB), dim3(256), 0, stream, M, T, D, kb);
    hipLaunchKernelGGL(kscale, dim3(NSTEP, BB), dim3(256), 0, stream, M, D, kb);
    hipLaunchKernelGGL(kupdate, dim3(NSTEP, NSTEP - 1, BB), dim3(256), 0, stream, M, T, D, kb);
  }
  hipLaunchKernelGGL(kfinal, dim3(16, 16, BB), dim3(256), 0, stream, sc, M, out, mk);
}